// Round 1
// baseline (435.418 us; speedup 1.0000x reference)
//
#include <hip/hip_runtime.h>
#include <math.h>

#define B    16
#define CIN  32
#define COUT 32
#define G    256
#define MXM  16
#define MYM  16
#define NKX  32   // 2*MXM retained kx modes: 0..15 and 240..255

// twiddle table: tw[m] = (cos(2*pi*m/256), sin(2*pi*m/256))
// forward DFT uses e^{-i th} = (c, -s); inverse uses e^{+i th} = (c, +s)

// ---------------------------------------------------------------------------
// Kernel 1: forward truncated DFT. One block per (b, cin) image.
// Phase 1: T[nx][ky] = sum_ny x[nx][ny] e^{-2pi i ky ny/256}   (ky 0..15)
// Phase 2: X[kxi][ky] = sum_nx T[nx][ky] e^{-2pi i kx nx/256}  (32 kx modes)
// X layout: [B][NKX][MYM][CIN] float2
// ---------------------------------------------------------------------------
__global__ __launch_bounds__(256) void k_fwd(const float* __restrict__ x,
                                             float2* __restrict__ X) {
    __shared__ float2 tw[256];
    __shared__ __align__(16) float rowbuf[4][256];
    __shared__ float2 T[256][16];          // 32 KB
    int t = threadIdx.x;
    {
        double ang = (double)t * (M_PI / 128.0);   // 2*pi*t/256
        tw[t] = make_float2((float)cos(ang), (float)sin(ang));
    }
    int img = blockIdx.x;                  // b*CIN + ci
    const float* xp = x + (size_t)img * (G * G);
    int wave = t >> 6, lane = t & 63;
    int ky = lane & 15, seg = lane >> 4;
    __syncthreads();

    for (int r0 = 0; r0 < G; r0 += 4) {
        int nx = r0 + wave;
        float4 v = reinterpret_cast<const float4*>(xp + (size_t)nx * G)[lane];
        reinterpret_cast<float4*>(rowbuf[wave])[lane] = v;
        __syncthreads();
        // lane (ky, seg): partial sum over ny in [seg*64, seg*64+64)
        float ar = 0.f, ai = 0.f;
        int idx = (ky * seg * 64) & 255;
        #pragma unroll 16
        for (int j = 0; j < 64; ++j) {
            float xv = rowbuf[wave][seg * 64 + j];
            float2 w = tw[idx];
            ar = fmaf(xv,  w.x, ar);
            ai = fmaf(xv, -w.y, ai);
            idx = (idx + ky) & 255;
        }
        // reduce across the 4 segs (lane bits 4,5)
        ar += __shfl_xor(ar, 16); ai += __shfl_xor(ai, 16);
        ar += __shfl_xor(ar, 32); ai += __shfl_xor(ai, 32);
        if (seg == 0) T[nx][ky] = make_float2(ar, ai);
        __syncthreads();
    }

    // phase 2: thread (ky2 = t&15, kxi0 = t>>4), two kxi halves per thread
    int ky2 = t & 15, kxi0 = t >> 4;
    int b = img >> 5, ci = img & 31;
    #pragma unroll
    for (int half = 0; half < 2; ++half) {
        int kxi = kxi0 + half * 16;
        int kx  = (kxi < 16) ? kxi : (224 + kxi);   // 240 + (kxi-16)
        float xr = 0.f, xi = 0.f;
        int idx = 0;
        for (int nx = 0; nx < G; ++nx) {
            float2 tv = T[nx][ky2];
            float2 w  = tw[idx];
            xr = fmaf(tv.x, w.x, fmaf( tv.y, w.y, xr));
            xi = fmaf(tv.y, w.x, fmaf(-tv.x, w.y, xi));
            idx = (idx + kx) & 255;
        }
        X[(((size_t)b * NKX + kxi) * MYM + ky2) * CIN + ci] = make_float2(xr, xi);
    }
}

// ---------------------------------------------------------------------------
// Kernel 2: complex channel mixing. One block per (kxi, ky) mode site.
// Out[b][o] = sum_i X[b][i] * W[i][o]   (complex), W from w1 (kxi<16) or w2.
// Y layout: [B][COUT][NKX*MYM] float2
// ---------------------------------------------------------------------------
__global__ __launch_bounds__(256) void k_mix(const float2* __restrict__ X,
                                             const float* __restrict__ w1r,
                                             const float* __restrict__ w1i,
                                             const float* __restrict__ w2r,
                                             const float* __restrict__ w2i,
                                             float2* __restrict__ Y) {
    __shared__ float2 Ws[CIN][COUT];   // 8 KB
    __shared__ float2 Xs[B][CIN];      // 4 KB
    int t = threadIdx.x;
    int site = blockIdx.x;             // kxi*16 + ky
    int kxi = site >> 4, ky = site & 15;
    const float* wr; const float* wi; int kxl;
    if (kxi < 16) { wr = w1r; wi = w1i; kxl = kxi; }
    else          { wr = w2r; wi = w2i; kxl = kxi - 16; }
    int wofs = kxl * MYM + ky;
    #pragma unroll
    for (int p = t; p < CIN * COUT; p += 256) {        // p = i*32 + o
        Ws[p >> 5][p & 31] = make_float2(wr[p * 256 + wofs], wi[p * 256 + wofs]);
    }
    #pragma unroll
    for (int p = t; p < B * CIN; p += 256) {           // p = b*32 + i
        int bb = p >> 5, i = p & 31;
        Xs[bb][i] = X[(((size_t)bb * NKX + kxi) * MYM + ky) * CIN + i];
    }
    __syncthreads();
    #pragma unroll
    for (int p = t; p < B * COUT; p += 256) {          // p = b*32 + o
        int bb = p >> 5, o = p & 31;
        float yr = 0.f, yi = 0.f;
        #pragma unroll
        for (int i = 0; i < CIN; ++i) {
            float2 xv = Xs[bb][i];
            float2 wv = Ws[i][o];
            yr = fmaf(xv.x, wv.x, fmaf(-xv.y, wv.y, yr));
            yi = fmaf(xv.x, wv.y, fmaf( xv.y, wv.x, yi));
        }
        Y[((size_t)bb * COUT + o) * (NKX * MYM) + site] = make_float2(yr, yi);
    }
}

// ---------------------------------------------------------------------------
// Kernel 3: inverse. One block per (b, cout) image.
// Phase 1: U[nx][ky] = sum_kxi Y[kxi][ky] e^{+2pi i kx nx/256}
// Phase 2: y[nx][ny] = (1/65536)(Re U[nx][0] + 2*sum_{ky=1}^{15}(Ur c - Ui s))
//   (pocketfft c2r ignores Im of bin 0 -> take Re(U0) only)
// ---------------------------------------------------------------------------
__global__ __launch_bounds__(256) void k_inv(const float2* __restrict__ Y,
                                             float* __restrict__ out) {
    __shared__ float2 tw[256];
    __shared__ float2 Ys[NKX][MYM];    // 4 KB
    __shared__ float2 U[G][MYM];       // 32 KB
    int t = threadIdx.x;
    {
        double ang = (double)t * (M_PI / 128.0);
        tw[t] = make_float2((float)cos(ang), (float)sin(ang));
    }
    size_t bo = blockIdx.x;            // b*COUT + o
    const float2* yp = Y + bo * (NKX * MYM);
    #pragma unroll
    for (int p = t; p < NKX * MYM; p += 256)
        reinterpret_cast<float2*>(Ys)[p] = yp[p];
    __syncthreads();

    // phase 1: thread t = nx
    {
        int nx = t;
        float ur[16], ui[16];
        #pragma unroll
        for (int k = 0; k < 16; ++k) { ur[k] = 0.f; ui[k] = 0.f; }
        #pragma unroll 4
        for (int kxi = 0; kxi < NKX; ++kxi) {
            int kx = (kxi < 16) ? kxi : (224 + kxi);
            float2 w = tw[(kx * nx) & 255];     // e^{+i th} = (c, s)
            #pragma unroll
            for (int k = 0; k < 16; ++k) {
                float2 yv = Ys[kxi][k];
                ur[k] = fmaf(yv.x, w.x, fmaf(-yv.y, w.y, ur[k]));
                ui[k] = fmaf(yv.x, w.y, fmaf( yv.y, w.x, ui[k]));
            }
        }
        #pragma unroll
        for (int k = 0; k < 16; ++k) U[t][k] = make_float2(ur[k], ui[k]);
    }
    __syncthreads();

    // phase 2: thread t = ny, fixed twiddles per thread across all rows
    float tc[15], ts[15];
    #pragma unroll
    for (int k = 1; k < 16; ++k) {
        float2 w = tw[(k * t) & 255];
        tc[k - 1] = 2.f * w.x; ts[k - 1] = 2.f * w.y;
    }
    float* op = out + bo * (size_t)(G * G);
    for (int nx = 0; nx < G; ++nx) {
        float acc = U[nx][0].x;
        #pragma unroll
        for (int k = 1; k < 16; ++k) {
            float2 uv = U[nx][k];
            acc = fmaf(uv.x, tc[k - 1], fmaf(-uv.y, ts[k - 1], acc));
        }
        op[(size_t)nx * G + t] = acc * (1.0f / 65536.0f);
    }
}

extern "C" void kernel_launch(void* const* d_in, const int* in_sizes, int n_in,
                              void* d_out, int out_size, void* d_ws, size_t ws_size,
                              hipStream_t stream) {
    const float* x   = (const float*)d_in[0];
    const float* w1r = (const float*)d_in[1];
    const float* w1i = (const float*)d_in[2];
    const float* w2r = (const float*)d_in[3];
    const float* w2i = (const float*)d_in[4];
    float* out = (float*)d_out;

    float2* X = (float2*)d_ws;                          // 16*32*16*32*8 = 2 MB
    float2* Y = X + (size_t)B * NKX * MYM * CIN;        // 16*32*512*8   = 2 MB

    k_fwd<<<dim3(B * CIN),   dim3(256), 0, stream>>>(x, X);
    k_mix<<<dim3(NKX * MYM), dim3(256), 0, stream>>>(X, w1r, w1i, w2r, w2i, Y);
    k_inv<<<dim3(B * COUT),  dim3(256), 0, stream>>>(Y, out);
}

// Round 3
// 324.573 us; speedup vs baseline: 1.3415x; 1.3415x over previous
//
#include <hip/hip_runtime.h>
#include <math.h>

#define B     16
#define CIN   32
#define COUT  32
#define G     256
#define NSITE 512   // 32 kx-modes * 16 ky-modes

// bijective chunked XCD swizzle (nwg % 8 == 0): consecutive work chunks land
// on one XCD's L2 so sibling blocks share weight cachelines.
__device__ __forceinline__ int swz8(int bid, int nwg) {
    int q = nwg >> 3;
    return (bid & 7) * q + (bid >> 3);
}

// ---------------------------------------------------------------------------
// Kernel 1: forward truncated DFT. One block per (b, cin) image.
// Phase A: T[nx][ky] = sum_ny x[nx][ny] e^{-2pi i ky ny/256}   (ky 0..15)
//   thread = row nx; 16 complex accumulators + 16 register rotators
//   (refreshed exactly from tw every 32 steps). x staged in transposed
//   [32][257] tile (reads: lane-contiguous, 2-way = free), reg double-buffer.
// Phase B: X[kx][ky] = sum_nx T[nx][ky] e^{-2pi i kx nx/256}  (32 kx modes)
//   thread = (ky, kxg); T reads are 16-distinct-bank b64 (conflict-free),
//   twiddles are register rotators.
// X layout: [B*CIN][NSITE] float2
// ---------------------------------------------------------------------------
__global__ __launch_bounds__(256, 2) void k_fwd(const float* __restrict__ x,
                                                float2* __restrict__ X) {
    __shared__ float2 tw[256];          // 2 KB   tw[m] = (cos, sin)(2pi m/256)
    __shared__ float tile[32][257];     // 32.9 KB transposed x chunk
    __shared__ float2 T[256][17];       // 34.8 KB ny-DFT result (padded)
    const int t = threadIdx.x;
    {
        double ang = (double)t * (M_PI / 128.0);
        tw[t] = make_float2((float)cos(ang), (float)sin(ang));
    }
    const int img = blockIdx.x;
    const float* xp = x + (size_t)img * (G * G);

    float ar[16], ai[16], wr[16], wi[16], sr[16], si[16];
    #pragma unroll
    for (int k = 0; k < 16; ++k) { ar[k] = 0.f; ai[k] = 0.f; }
    __syncthreads();
    #pragma unroll
    for (int k = 0; k < 16; ++k) { sr[k] = tw[k].x; si[k] = -tw[k].y; }

    const int row0 = t >> 3, seg = t & 7;   // 32 rows x 8 float4-segs per pass
    float4 rs[8];
    #pragma unroll
    for (int p = 0; p < 8; ++p)
        rs[p] = *reinterpret_cast<const float4*>(xp + (size_t)(p * 32 + row0) * G + seg * 4);
    #pragma unroll
    for (int p = 0; p < 8; ++p) {
        int cc = seg * 4, rr = p * 32 + row0;
        tile[cc + 0][rr] = rs[p].x; tile[cc + 1][rr] = rs[p].y;
        tile[cc + 2][rr] = rs[p].z; tile[cc + 3][rr] = rs[p].w;
    }
    __syncthreads();

    for (int c = 0; c < 8; ++c) {
        const int ny0 = c * 32;
        if (c < 7) {   // issue next chunk's global loads before compute (T14)
            #pragma unroll
            for (int p = 0; p < 8; ++p)
                rs[p] = *reinterpret_cast<const float4*>(
                    xp + (size_t)(p * 32 + row0) * G + (ny0 + 32) + seg * 4);
        }
        // exact rotator refresh (wave-uniform broadcast reads)
        #pragma unroll
        for (int k = 0; k < 16; ++k) {
            float2 w0 = tw[(k * ny0) & 255];
            wr[k] = w0.x; wi[k] = -w0.y;
        }
        for (int j = 0; j < 32; ++j) {
            float xv = tile[j][t];          // banks (j+t)%32: 2-way = free
            #pragma unroll
            for (int k = 0; k < 16; ++k) {
                ar[k] = fmaf(xv, wr[k], ar[k]);
                ai[k] = fmaf(xv, wi[k], ai[k]);
                float nr = fmaf(wr[k], sr[k], -wi[k] * si[k]);
                wi[k]    = fmaf(wr[k], si[k],  wi[k] * sr[k]);
                wr[k] = nr;
            }
        }
        __syncthreads();
        if (c < 7) {
            #pragma unroll
            for (int p = 0; p < 8; ++p) {
                int cc = seg * 4, rr = p * 32 + row0;
                tile[cc + 0][rr] = rs[p].x; tile[cc + 1][rr] = rs[p].y;
                tile[cc + 2][rr] = rs[p].z; tile[cc + 3][rr] = rs[p].w;
            }
            __syncthreads();
        }
    }
    #pragma unroll
    for (int k = 0; k < 16; ++k) T[t][k] = make_float2(ar[k], ai[k]);
    __syncthreads();

    // ---- phase B ----
    const int ky = t & 15, kxg = t >> 4;    // kxg 0..15; modes kxg and 240+kxg
    float x1r = 0.f, x1i = 0.f, x2r = 0.f, x2i = 0.f;
    float w1r = 1.f, w1i = 0.f, w2r = 1.f, w2i = 0.f;
    const float s1r = tw[kxg].x,      s1i = -tw[kxg].y;       // e^{-2pi i kxg/256}
    const float s2r = tw[16 - kxg].x, s2i =  tw[16 - kxg].y;  // e^{+2pi i (16-kxg)/256}
    for (int c = 0; c < 8; ++c) {
        const int nx0 = c * 32;
        {   // exact refresh (rare; minor conflicts acceptable)
            int e1 = (kxg * nx0) & 255;
            w1r = tw[e1].x; w1i = -tw[e1].y;
            int e2 = ((16 - kxg) * nx0) & 255;
            w2r = tw[e2].x; w2i = tw[e2].y;
        }
        for (int j = 0; j < 32; ++j) {
            float2 tv = T[nx0 + j][ky];    // 16 distinct banks + broadcast: free
            x1r = fmaf(tv.x, w1r, fmaf(-tv.y, w1i, x1r));
            x1i = fmaf(tv.x, w1i, fmaf( tv.y, w1r, x1i));
            x2r = fmaf(tv.x, w2r, fmaf(-tv.y, w2i, x2r));
            x2i = fmaf(tv.x, w2i, fmaf( tv.y, w2r, x2i));
            float n1 = fmaf(w1r, s1r, -w1i * s1i);
            w1i      = fmaf(w1r, s1i,  w1i * s1r);
            w1r = n1;
            float n2 = fmaf(w2r, s2r, -w2i * s2i);
            w2i      = fmaf(w2r, s2i,  w2i * s2r);
            w2r = n2;
        }
    }
    float2* Xp = X + (size_t)img * NSITE;
    Xp[kxg * 16 + ky]        = make_float2(x1r, x1i);   // site = kxi*16+ky = t
    Xp[(kxg + 16) * 16 + ky] = make_float2(x2r, x2i);
}

// ---------------------------------------------------------------------------
// Kernel 2: complex channel mixing. One block per mode site (XCD-swizzled).
// Out[b][o] = sum_i X[b][i] * W[i][o]  (complex); W from w1 (kxi<16) else w2.
// Y layout: [B*COUT][NSITE] float2
// ---------------------------------------------------------------------------
__global__ __launch_bounds__(256) void k_mix(const float2* __restrict__ X,
                                             const float* __restrict__ w1r,
                                             const float* __restrict__ w1i,
                                             const float* __restrict__ w2r,
                                             const float* __restrict__ w2i,
                                             float2* __restrict__ Y) {
    __shared__ float2 Ws[CIN][COUT];   // 8 KB
    __shared__ float2 Xs[B][CIN];      // 4 KB
    const int t = threadIdx.x;
    const int site = swz8(blockIdx.x, NSITE);
    const int kxi = site >> 4, kky = site & 15;
    const float* wr; const float* wi; int kxl;
    if (kxi < 16) { wr = w1r; wi = w1i; kxl = kxi; }
    else          { wr = w2r; wi = w2i; kxl = kxi - 16; }
    const int wofs = kxl * 16 + kky;
    for (int p = t; p < CIN * COUT; p += 256)          // p = i*32 + o
        Ws[p >> 5][p & 31] = make_float2(wr[p * 256 + wofs], wi[p * 256 + wofs]);
    for (int p = t; p < B * CIN; p += 256) {           // p = b*32 + i
        int bb = p >> 5, i = p & 31;
        Xs[bb][i] = X[(size_t)(bb * CIN + i) * NSITE + site];
    }
    __syncthreads();
    for (int p = t; p < B * COUT; p += 256) {          // p = b*32 + o
        int bb = p >> 5, o = p & 31;
        float yr = 0.f, yi = 0.f;
        #pragma unroll
        for (int i = 0; i < CIN; ++i) {
            float2 xv = Xs[bb][i];
            float2 wv = Ws[i][o];
            yr = fmaf(xv.x, wv.x, fmaf(-xv.y, wv.y, yr));
            yi = fmaf(xv.x, wv.y, fmaf( xv.y, wv.x, yi));
        }
        Y[(size_t)(bb * COUT + o) * NSITE + site] = make_float2(yr, yi);
    }
}

// ---------------------------------------------------------------------------
// Kernel 3: inverse. One block per (b, cout) image.
// Phase 1: U[nx][ky] = sum_kxi Ys[kxi][ky] e^{+2pi i kx nx/256}
//   thread = nx; Ys rows read as wave-uniform float4 broadcasts; per-lane
//   rotator w(nx) advanced by e^{+2pi i nx/256} per kxi (<=16 steps: exact).
// Phase 2: y[nx][ny] = (1/65536)(Re U0 + 2*sum_k (Ur cos - Ui sin))
//   wave w owns rows [w*64, w*64+64); U row loaded once to regs (8 bcast
//   float4) and reused for 4 ny-blocks via exact i^k twiddle rotation.
// ---------------------------------------------------------------------------
__global__ __launch_bounds__(256, 2) void k_inv(const float2* __restrict__ Y,
                                                float* __restrict__ out) {
    __shared__ float2 tw[256];      // 2 KB
    __shared__ float2 Ys[32][16];   // 4 KB, rows 128 B (float4-aligned)
    __shared__ float2 U[256][18];   // 36.9 KB (stride 144 B: aligned + fewer conflicts)
    const int t = threadIdx.x;
    {
        double ang = (double)t * (M_PI / 128.0);
        tw[t] = make_float2((float)cos(ang), (float)sin(ang));
    }
    const int img = blockIdx.x;
    const float2* yp = Y + (size_t)img * NSITE;
    reinterpret_cast<float4*>(Ys)[t] = reinterpret_cast<const float4*>(yp)[t];
    __syncthreads();

    // ---- phase 1: thread t = nx ----
    float ur[16], ui[16];
    #pragma unroll
    for (int k = 0; k < 16; ++k) { ur[k] = 0.f; ui[k] = 0.f; }
    const float str = tw[t].x, sti = tw[t].y;   // e^{+2pi i nx/256}
    float wr = 1.f, wi = 0.f;                   // kx=0
    #pragma unroll 2
    for (int kxi = 0; kxi < 16; ++kxi) {
        const float4* yrow = reinterpret_cast<const float4*>(Ys[kxi]);
        #pragma unroll
        for (int q = 0; q < 8; ++q) {
            float4 v = yrow[q];                 // uniform addr: broadcast
            ur[2*q]   = fmaf(v.x, wr, fmaf(-v.y, wi, ur[2*q]));
            ui[2*q]   = fmaf(v.x, wi, fmaf( v.y, wr, ui[2*q]));
            ur[2*q+1] = fmaf(v.z, wr, fmaf(-v.w, wi, ur[2*q+1]));
            ui[2*q+1] = fmaf(v.z, wi, fmaf( v.w, wr, ui[2*q+1]));
        }
        float nr = fmaf(wr, str, -wi * sti);
        wi       = fmaf(wr, sti,  wi * str);
        wr = nr;
    }
    {   // restart at kx=240: w = e^{-2pi i 16 nx/256} (16 distinct addrs, once)
        int e = (16 * t) & 255;
        wr = tw[e].x; wi = -tw[e].y;
    }
    #pragma unroll 2
    for (int kxi = 16; kxi < 32; ++kxi) {
        const float4* yrow = reinterpret_cast<const float4*>(Ys[kxi]);
        #pragma unroll
        for (int q = 0; q < 8; ++q) {
            float4 v = yrow[q];
            ur[2*q]   = fmaf(v.x, wr, fmaf(-v.y, wi, ur[2*q]));
            ui[2*q]   = fmaf(v.x, wi, fmaf( v.y, wr, ui[2*q]));
            ur[2*q+1] = fmaf(v.z, wr, fmaf(-v.w, wi, ur[2*q+1]));
            ui[2*q+1] = fmaf(v.z, wi, fmaf( v.w, wr, ui[2*q+1]));
        }
        float nr = fmaf(wr, str, -wi * sti);
        wi       = fmaf(wr, sti,  wi * str);
        wr = nr;
    }
    #pragma unroll
    for (int k = 0; k < 16; ++k) U[t][k] = make_float2(ur[k], ui[k]);
    __syncthreads();

    // ---- phase 2: wave wv owns rows [wv*64, wv*64+64), lane = ny base ----
    const int wv = t >> 6, ln = t & 63;
    float tc[16], ts[16];
    #pragma unroll
    for (int k = 1; k < 16; ++k) {
        float2 w = tw[(k * ln) & 255];
        tc[k] = 2.f * w.x; ts[k] = 2.f * w.y;
    }
    float* op = out + (size_t)img * (G * G);
    for (int r = 0; r < 64; ++r) {
        const int nx = wv * 64 + r;
        float4 u[8];
        #pragma unroll
        for (int q = 0; q < 8; ++q)
            u[q] = reinterpret_cast<const float4*>(U[nx])[q];   // broadcast
        #pragma unroll
        for (int nb = 0; nb < 4; ++nb) {   // ny = nb*64 + ln; e^{i th} *= i^{k*nb}
            float acc = u[0].x;            // c2r ignores Im of bin 0
            #pragma unroll
            for (int k = 1; k < 16; ++k) {
                float urk = (k & 1) ? u[k >> 1].z : u[k >> 1].x;
                float uik = (k & 1) ? u[k >> 1].w : u[k >> 1].y;
                const int m = (k * nb) & 3;
                if (m == 0)      acc = fmaf(urk, tc[k], fmaf(-uik, ts[k], acc));
                else if (m == 1) acc = fmaf(-urk, ts[k], fmaf(-uik, tc[k], acc));
                else if (m == 2) acc = fmaf(-urk, tc[k], fmaf( uik, ts[k], acc));
                else             acc = fmaf( urk, ts[k], fmaf( uik, tc[k], acc));
            }
            op[(size_t)nx * G + nb * 64 + ln] = acc * (1.0f / 65536.0f);
        }
    }
}

extern "C" void kernel_launch(void* const* d_in, const int* in_sizes, int n_in,
                              void* d_out, int out_size, void* d_ws, size_t ws_size,
                              hipStream_t stream) {
    const float* x   = (const float*)d_in[0];
    const float* w1r = (const float*)d_in[1];
    const float* w1i = (const float*)d_in[2];
    const float* w2r = (const float*)d_in[3];
    const float* w2i = (const float*)d_in[4];
    float* out = (float*)d_out;

    float2* X = (float2*)d_ws;                       // 512*512*8 = 2 MB
    float2* Y = X + (size_t)B * CIN * NSITE;         // 2 MB

    k_fwd<<<dim3(B * CIN),  dim3(256), 0, stream>>>(x, X);
    k_mix<<<dim3(NSITE),    dim3(256), 0, stream>>>(X, w1r, w1i, w2r, w2i, Y);
    k_inv<<<dim3(B * COUT), dim3(256), 0, stream>>>(Y, out);
}

// Round 4
// 304.934 us; speedup vs baseline: 1.4279x; 1.0644x over previous
//
#include <hip/hip_runtime.h>
#include <math.h>

#define B     16
#define CIN   32
#define COUT  32
#define G     256
#define NSITE 512   // 32 kx-modes * 16 ky-modes

// bijective chunked XCD swizzle (nwg % 8 == 0)
__device__ __forceinline__ int swz8(int bid, int nwg) {
    int q = nwg >> 3;
    return (bid & 7) * q + (bid >> 3);
}

// ---------------------------------------------------------------------------
// Kernel 1: forward truncated DFT. One block per (b, cin) image.
// Phase A (radix-2 over ny): pair (m, m+128), m<128:
//   T[k] = sum_{m<128} W^{km} * (x[m] + (-1)^k x[m+128]),  W = e^{-2pi i/256}
//   thread = row nx; 16 complex accumulators + 15 register rotators
//   (refreshed exactly every 16 steps). Chunks stage ny in {m0..m0+15} u
//   {m0+128..m0+143}: 64-B aligned runs, each ny fetched exactly once.
// Phase B (radix-2 over nx): outputs kxg and 240+kxg share parity ->
//   shared butterfly p = T[nx] + (-1)^kxg T[nx+128], nx<128.
// X layout: [B*CIN][NSITE] float2
// ---------------------------------------------------------------------------
__global__ __launch_bounds__(256, 2) void k_fwd(const float* __restrict__ x,
                                                float2* __restrict__ X) {
    __shared__ float2 tw[256];          // tw[m] = (cos, sin)(2pi m/256)
    __shared__ float tile[32][257];     // 32.9 KB: rows r<16: ny=m0+r; r>=16: ny=m0+128+(r-16)
    __shared__ float2 T[256][17];       // 34.8 KB
    const int t = threadIdx.x;
    {
        double ang = (double)t * (M_PI / 128.0);
        tw[t] = make_float2((float)cos(ang), (float)sin(ang));
    }
    const int img = blockIdx.x;
    const float* xp = x + (size_t)img * (G * G);

    float tr[16], ti[16], wr[16], wi[16], sr[16], si[16];
    #pragma unroll
    for (int k = 0; k < 16; ++k) { tr[k] = 0.f; ti[k] = 0.f; }
    __syncthreads();
    #pragma unroll
    for (int k = 1; k < 16; ++k) { sr[k] = tw[k].x; si[k] = -tw[k].y; }

    // staging: idx = p*256+t -> nx = idx>>3, sub = idx&7 (h = sub>>2, q = sub&3)
    // global float4 at xp[nx*256 + m0 + 128h + 4q]; tile row r = 16h + 4q + j
    float4 rs[8];
    #pragma unroll
    for (int p = 0; p < 8; ++p) {
        int idx = p * 256 + t, nx = idx >> 3, sub = idx & 7, h = sub >> 2, q = sub & 3;
        rs[p] = *reinterpret_cast<const float4*>(xp + (size_t)nx * G + (128 * h + 4 * q));
    }
    #pragma unroll
    for (int p = 0; p < 8; ++p) {
        int idx = p * 256 + t, nx = idx >> 3, sub = idx & 7, h = sub >> 2, q = sub & 3;
        int r = 16 * h + 4 * q;
        tile[r + 0][nx] = rs[p].x; tile[r + 1][nx] = rs[p].y;
        tile[r + 2][nx] = rs[p].z; tile[r + 3][nx] = rs[p].w;
    }
    __syncthreads();

    for (int c = 0; c < 8; ++c) {
        const int m0 = c * 16;
        if (c < 7) {   // issue next chunk's loads before compute
            #pragma unroll
            for (int p = 0; p < 8; ++p) {
                int idx = p * 256 + t, nx = idx >> 3, sub = idx & 7, h = sub >> 2, q = sub & 3;
                rs[p] = *reinterpret_cast<const float4*>(
                    xp + (size_t)nx * G + (m0 + 16 + 128 * h + 4 * q));
            }
        }
        // exact rotator refresh: w[k] = e^{-2pi i k m0/256} (wave-uniform reads)
        #pragma unroll
        for (int k = 1; k < 16; ++k) {
            float2 w0 = tw[(k * m0) & 255];
            wr[k] = w0.x; wi[k] = -w0.y;
        }
        #pragma unroll
        for (int e = 0; e < 16; ++e) {
            float x0 = tile[e][t], x1 = tile[16 + e][t];
            float ev = x0 + x1, od = x0 - x1;
            tr[0] += ev;
            #pragma unroll
            for (int k = 1; k < 16; ++k) {
                float s_ = (k & 1) ? od : ev;
                tr[k] = fmaf(s_, wr[k], tr[k]);
                ti[k] = fmaf(s_, wi[k], ti[k]);
                float nr = fmaf(wr[k], sr[k], -wi[k] * si[k]);
                wi[k]   = fmaf(wr[k], si[k],  wi[k] * sr[k]);
                wr[k] = nr;
            }
        }
        __syncthreads();
        if (c < 7) {
            #pragma unroll
            for (int p = 0; p < 8; ++p) {
                int idx = p * 256 + t, nx = idx >> 3, sub = idx & 7, h = sub >> 2, q = sub & 3;
                int r = 16 * h + 4 * q;
                tile[r + 0][nx] = rs[p].x; tile[r + 1][nx] = rs[p].y;
                tile[r + 2][nx] = rs[p].z; tile[r + 3][nx] = rs[p].w;
            }
            __syncthreads();
        }
    }
    #pragma unroll
    for (int k = 0; k < 16; ++k) T[t][k] = make_float2(tr[k], ti[k]);
    __syncthreads();

    // ---- phase B ----
    const int ky = t & 15, kxg = t >> 4;    // outputs: kxg and 240+kxg (same parity)
    float x1r = 0.f, x1i = 0.f, x2r = 0.f, x2i = 0.f;
    const float sgn = 1.f - 2.f * (float)(kxg & 1);
    const float s1r = tw[kxg].x,      s1i = -tw[kxg].y;       // e^{-2pi i kxg/256}
    const float s2r = tw[16 - kxg].x, s2i =  tw[16 - kxg].y;  // e^{+2pi i (16-kxg)/256}
    for (int c2 = 0; c2 < 4; ++c2) {
        const int nx0 = c2 * 32;
        int e1 = (kxg * nx0) & 255;
        float w1r_ = tw[e1].x, w1i_ = -tw[e1].y;
        int e2 = ((16 - kxg) * nx0) & 255;
        float w2r_ = tw[e2].x, w2i_ = tw[e2].y;
        #pragma unroll
        for (int j = 0; j < 32; ++j) {
            float2 a = T[nx0 + j][ky];
            float2 b = T[128 + nx0 + j][ky];
            float pr = fmaf(sgn, b.x, a.x);
            float pi = fmaf(sgn, b.y, a.y);
            x1r = fmaf(pr, w1r_, fmaf(-pi, w1i_, x1r));
            x1i = fmaf(pr, w1i_, fmaf( pi, w1r_, x1i));
            x2r = fmaf(pr, w2r_, fmaf(-pi, w2i_, x2r));
            x2i = fmaf(pr, w2i_, fmaf( pi, w2r_, x2i));
            float n1 = fmaf(w1r_, s1r, -w1i_ * s1i);
            w1i_     = fmaf(w1r_, s1i,  w1i_ * s1r);
            w1r_ = n1;
            float n2 = fmaf(w2r_, s2r, -w2i_ * s2i);
            w2i_     = fmaf(w2r_, s2i,  w2i_ * s2r);
            w2r_ = n2;
        }
    }
    float2* Xp = X + (size_t)img * NSITE;
    Xp[kxg * 16 + ky]        = make_float2(x1r, x1i);
    Xp[(kxg + 16) * 16 + ky] = make_float2(x2r, x2i);
}

// ---------------------------------------------------------------------------
// Kernel 2: complex channel mixing (unchanged). One block per site, swizzled.
// ---------------------------------------------------------------------------
__global__ __launch_bounds__(256) void k_mix(const float2* __restrict__ X,
                                             const float* __restrict__ w1r,
                                             const float* __restrict__ w1i,
                                             const float* __restrict__ w2r,
                                             const float* __restrict__ w2i,
                                             float2* __restrict__ Y) {
    __shared__ float2 Ws[CIN][COUT];
    __shared__ float2 Xs[B][CIN];
    const int t = threadIdx.x;
    const int site = swz8(blockIdx.x, NSITE);
    const int kxi = site >> 4, kky = site & 15;
    const float* wr; const float* wi; int kxl;
    if (kxi < 16) { wr = w1r; wi = w1i; kxl = kxi; }
    else          { wr = w2r; wi = w2i; kxl = kxi - 16; }
    const int wofs = kxl * 16 + kky;
    for (int p = t; p < CIN * COUT; p += 256)
        Ws[p >> 5][p & 31] = make_float2(wr[p * 256 + wofs], wi[p * 256 + wofs]);
    for (int p = t; p < B * CIN; p += 256) {
        int bb = p >> 5, i = p & 31;
        Xs[bb][i] = X[(size_t)(bb * CIN + i) * NSITE + site];
    }
    __syncthreads();
    for (int p = t; p < B * COUT; p += 256) {
        int bb = p >> 5, o = p & 31;
        float yr = 0.f, yi = 0.f;
        #pragma unroll
        for (int i = 0; i < CIN; ++i) {
            float2 xv = Xs[bb][i];
            float2 wv = Ws[i][o];
            yr = fmaf(xv.x, wv.x, fmaf(-xv.y, wv.y, yr));
            yi = fmaf(xv.x, wv.y, fmaf( xv.y, wv.x, yi));
        }
        Y[(size_t)(bb * COUT + o) * NSITE + site] = make_float2(yr, yi);
    }
}

// ---------------------------------------------------------------------------
// Kernel 3: inverse, 4-way nx-split. Block = (img, Q); rows nx in [64Q,64Q+64).
// Phase 1: U[nxl][k] = sum_kxi Ys[kxi][k] e^{+2pi i kx nx/256}
//   thread = (nxl = t&63, kg = t>>6) -> 4 k's; Ys reads wave-uniform float4;
//   per-lane rotator advanced by e^{+2pi i nx/256} (<=16 steps, exact refresh).
// Phase 2: y[nx][ny] = (1/65536)(Re U0 + 2*sum_k(Ur c - Ui s)); wave owns 16
//   rows; U row broadcast to regs, reused for 4 ny-blocks via i^k rotation.
// LDS 15.3 KB -> high occupancy; grid 2048.
// ---------------------------------------------------------------------------
__global__ __launch_bounds__(256, 4) void k_inv(const float2* __restrict__ Y,
                                                float* __restrict__ out) {
    __shared__ float2 tw[256];
    __shared__ __align__(16) float2 Ys[32][16];   // 4 KB
    __shared__ __align__(16) float2 U[64][18];    // 9.2 KB (144-B rows, 16-B aligned)
    const int t = threadIdx.x;
    {
        double ang = (double)t * (M_PI / 128.0);
        tw[t] = make_float2((float)cos(ang), (float)sin(ang));
    }
    const int img = blockIdx.x >> 2, Q = blockIdx.x & 3;
    const float2* yp = Y + (size_t)img * NSITE;
    reinterpret_cast<float4*>(Ys)[t] = reinterpret_cast<const float4*>(yp)[t];
    __syncthreads();

    // ---- phase 1 ----
    const int nxl = t & 63, kg = t >> 6;
    const int nx = Q * 64 + nxl;
    float ur[4], ui[4];
    #pragma unroll
    for (int j = 0; j < 4; ++j) { ur[j] = 0.f; ui[j] = 0.f; }
    const float str = tw[nx].x, sti = tw[nx].y;   // e^{+2pi i nx/256}
    float wr = 1.f, wi = 0.f;
    #pragma unroll 4
    for (int kxi = 0; kxi < 16; ++kxi) {
        float4 a = reinterpret_cast<const float4*>(Ys[kxi])[2 * kg];
        float4 b = reinterpret_cast<const float4*>(Ys[kxi])[2 * kg + 1];
        ur[0] = fmaf(a.x, wr, fmaf(-a.y, wi, ur[0])); ui[0] = fmaf(a.x, wi, fmaf(a.y, wr, ui[0]));
        ur[1] = fmaf(a.z, wr, fmaf(-a.w, wi, ur[1])); ui[1] = fmaf(a.z, wi, fmaf(a.w, wr, ui[1]));
        ur[2] = fmaf(b.x, wr, fmaf(-b.y, wi, ur[2])); ui[2] = fmaf(b.x, wi, fmaf(b.y, wr, ui[2]));
        ur[3] = fmaf(b.z, wr, fmaf(-b.w, wi, ur[3])); ui[3] = fmaf(b.z, wi, fmaf(b.w, wr, ui[3]));
        float nr = fmaf(wr, str, -wi * sti); wi = fmaf(wr, sti, wi * str); wr = nr;
    }
    {   // restart at kx=240: w = e^{-2pi i 16 nx/256}
        int e = (16 * nx) & 255;
        wr = tw[e].x; wi = -tw[e].y;
    }
    #pragma unroll 4
    for (int kxi = 16; kxi < 32; ++kxi) {
        float4 a = reinterpret_cast<const float4*>(Ys[kxi])[2 * kg];
        float4 b = reinterpret_cast<const float4*>(Ys[kxi])[2 * kg + 1];
        ur[0] = fmaf(a.x, wr, fmaf(-a.y, wi, ur[0])); ui[0] = fmaf(a.x, wi, fmaf(a.y, wr, ui[0]));
        ur[1] = fmaf(a.z, wr, fmaf(-a.w, wi, ur[1])); ui[1] = fmaf(a.z, wi, fmaf(a.w, wr, ui[1]));
        ur[2] = fmaf(b.x, wr, fmaf(-b.y, wi, ur[2])); ui[2] = fmaf(b.x, wi, fmaf(b.y, wr, ui[2]));
        ur[3] = fmaf(b.z, wr, fmaf(-b.w, wi, ur[3])); ui[3] = fmaf(b.z, wi, fmaf(b.w, wr, ui[3]));
        float nr = fmaf(wr, str, -wi * sti); wi = fmaf(wr, sti, wi * str); wr = nr;
    }
    #pragma unroll
    for (int j = 0; j < 4; ++j) U[nxl][4 * kg + j] = make_float2(ur[j], ui[j]);
    __syncthreads();

    // ---- phase 2: wave wv owns rows rl in [wv*16, wv*16+16) ----
    const int wv = t >> 6, ln = t & 63;
    float tc[16], ts[16];
    #pragma unroll
    for (int k = 1; k < 16; ++k) {
        float2 w = tw[(k * ln) & 255];
        tc[k] = 2.f * w.x; ts[k] = 2.f * w.y;
    }
    float* op = out + (size_t)img * (G * G);
    for (int r = 0; r < 16; ++r) {
        const int rl = wv * 16 + r;
        const int nxg = Q * 64 + rl;
        float4 u[8];
        #pragma unroll
        for (int q = 0; q < 8; ++q)
            u[q] = reinterpret_cast<const float4*>(U[rl])[q];   // broadcast
        #pragma unroll
        for (int nb = 0; nb < 4; ++nb) {
            float acc = u[0].x;
            #pragma unroll
            for (int k = 1; k < 16; ++k) {
                float urk = (k & 1) ? u[k >> 1].z : u[k >> 1].x;
                float uik = (k & 1) ? u[k >> 1].w : u[k >> 1].y;
                const int m = (k * nb) & 3;
                if (m == 0)      acc = fmaf(urk, tc[k], fmaf(-uik, ts[k], acc));
                else if (m == 1) acc = fmaf(-urk, ts[k], fmaf(-uik, tc[k], acc));
                else if (m == 2) acc = fmaf(-urk, tc[k], fmaf( uik, ts[k], acc));
                else             acc = fmaf( urk, ts[k], fmaf( uik, tc[k], acc));
            }
            op[(size_t)nxg * G + nb * 64 + ln] = acc * (1.0f / 65536.0f);
        }
    }
}

extern "C" void kernel_launch(void* const* d_in, const int* in_sizes, int n_in,
                              void* d_out, int out_size, void* d_ws, size_t ws_size,
                              hipStream_t stream) {
    const float* x   = (const float*)d_in[0];
    const float* w1r = (const float*)d_in[1];
    const float* w1i = (const float*)d_in[2];
    const float* w2r = (const float*)d_in[3];
    const float* w2i = (const float*)d_in[4];
    float* out = (float*)d_out;

    float2* X = (float2*)d_ws;                       // 2 MB
    float2* Y = X + (size_t)B * CIN * NSITE;         // 2 MB

    k_fwd<<<dim3(B * CIN),      dim3(256), 0, stream>>>(x, X);
    k_mix<<<dim3(NSITE),        dim3(256), 0, stream>>>(X, w1r, w1i, w2r, w2i, Y);
    k_inv<<<dim3(B * COUT * 4), dim3(256), 0, stream>>>(Y, out);
}